// Round 7
// baseline (563.690 us; speedup 1.0000x reference)
//
#include <hip/hip_runtime.h>
#include <hip/hip_bf16.h>

#define FDIM 64
#define LFP 128
#define RROUNDS 4
#define BM 64      // nodes per block in mlp kernel
#define SCAN_B 1024

typedef __attribute__((ext_vector_type(8))) short bf16x8;
typedef __attribute__((ext_vector_type(4))) float f32x4;

__device__ __forceinline__ float bf2f(unsigned short u) {
    unsigned int x = ((unsigned int)u) << 16;
    float f;
    __builtin_memcpy(&f, &x, 4);
    return f;
}
__device__ __forceinline__ unsigned short f2bf(float x) {
    unsigned int u;
    __builtin_memcpy(&u, &x, 4);
    unsigned int r = (u + 0x7fffu + ((u >> 16) & 1u)) >> 16;  // RNE
    return (unsigned short)r;
}

// ---------------- CSR build ----------------
__global__ void hist_kernel(const int* __restrict__ dst, int* __restrict__ cnt, int nE) {
    int e = blockIdx.x * blockDim.x + threadIdx.x;
    if (e < nE) atomicAdd(&cnt[dst[e]], 1);
}

__global__ __launch_bounds__(256) void scan1_kernel(const int* __restrict__ cnt,
                                                    int* __restrict__ rp, int* __restrict__ bsum, int n) {
    __shared__ int s[256];
    int t = threadIdx.x;
    int base = blockIdx.x * SCAN_B;
    int v[4], sum = 0;
#pragma unroll
    for (int i = 0; i < 4; i++) {
        int idx = base + t * 4 + i;
        v[i] = (idx < n) ? cnt[idx] : 0;
        sum += v[i];
    }
    s[t] = sum;
    __syncthreads();
    for (int d = 1; d < 256; d <<= 1) {
        int x = (t >= d) ? s[t - d] : 0;
        __syncthreads();
        s[t] += x;
        __syncthreads();
    }
    int excl = (t > 0) ? s[t - 1] : 0;
#pragma unroll
    for (int i = 0; i < 4; i++) {
        int idx = base + t * 4 + i;
        if (idx < n) { rp[idx] = excl; excl += v[i]; }
    }
    if (t == 255) bsum[blockIdx.x] = s[255];
}

// scan3 with scan2 merged: each block redoes the (nb<=64) block-sum wave scan.
__global__ __launch_bounds__(256) void scan3_kernel(int* __restrict__ rp, const int* __restrict__ bsum,
                                                    int* __restrict__ cursor, int nb, int n, int nE) {
    __shared__ int sB[64];
    int t = threadIdx.x;
    if (t < 64) {  // wave 0: exclusive scan of block sums (nb == 49 here)
        int v = (t < nb) ? bsum[t] : 0;
#pragma unroll
        for (int d = 1; d < 64; d <<= 1) {
            int x = __shfl_up(v, d);
            if (t >= d) v += x;
        }
        int e = __shfl_up(v, 1);
        if (t == 0) e = 0;
        sB[t] = e;
    }
    __syncthreads();
    int idx = blockIdx.x * blockDim.x + t;
    if (idx < n) {
        int v = rp[idx] + sB[idx / SCAN_B];
        rp[idx] = v;
        cursor[idx] = v;
    }
    if (idx == n) rp[n] = nE;
}

__global__ void fill_kernel(const int* __restrict__ src, const int* __restrict__ dst,
                            int* __restrict__ cursor, int* __restrict__ csr, int nE) {
    int e = blockIdx.x * blockDim.x + threadIdx.x;
    if (e < nE) {
        int p = atomicAdd(&cursor[dst[e]], 1);
        csr[p] = src[e];
    }
}

// ---------------- pipeline ----------------
__global__ void prep_kernel(const float* __restrict__ Wh, const float* __restrict__ Wfp,
                            unsigned short* __restrict__ whT, unsigned short* __restrict__ wfpT) {
    int o = blockIdx.x * blockDim.x + threadIdx.x;
    if (o < RROUNDS * FDIM * FDIM) {
        int r = o >> 12, rem = o & 4095, j = rem >> 6, k = rem & 63;
        whT[o] = f2bf(Wh[r * 4096 + k * 64 + j]);
    } else {
        int o2 = o - RROUNDS * FDIM * FDIM;
        int r = o2 >> 13, rem = o2 & 8191, l = rem >> 6, k = rem & 63;
        wfpT[o2] = f2bf(Wfp[r * 8192 + k * 128 + l]);
    }
}

__global__ void init_kernel(const int* __restrict__ feat, const float* __restrict__ table,
                            unsigned short* __restrict__ emb, float* __restrict__ f, int n) {
    int gid = blockIdx.x * blockDim.x + threadIdx.x;
    if (gid < n * FDIM) {
        int node = gid >> 6;
        int d = gid & 63;
        emb[gid] = f2bf(table[feat[node] * FDIM + d]);
    }
    if (gid < LFP) f[gid] = 0.f;
}

// one wave per node: v[n] = emb[n] + sum_{nbr} emb[nbr], via CSR.
// 8 neighbors/iter x 8 lanes x bf16x8(16B) = one full 128B emb row per neighbor.
__global__ __launch_bounds__(256) void gather_kernel(
        const unsigned short* __restrict__ emb, const int* __restrict__ rp,
        const int* __restrict__ csr, unsigned short* __restrict__ vbuf, int N) {
    int wid = (int)((blockIdx.x * 256 + threadIdx.x) >> 6);
    int lane = threadIdx.x & 63;
    if (wid >= N) return;
    int start = rp[wid], end = rp[wid + 1];
    int grp = lane >> 3, q = lane & 7;
    float acc[8] = {0.f, 0.f, 0.f, 0.f, 0.f, 0.f, 0.f, 0.f};
    for (int j = start + grp; j < end; j += 8) {
        int nb = csr[j];
        bf16x8 u = *reinterpret_cast<const bf16x8*>(emb + (size_t)nb * 64 + q * 8);
#pragma unroll
        for (int x = 0; x < 8; ++x) acc[x] += bf2f((unsigned short)u[x]);
    }
#pragma unroll
    for (int x = 0; x < 8; ++x) {
        acc[x] += __shfl_xor(acc[x], 8);
        acc[x] += __shfl_xor(acc[x], 16);
        acc[x] += __shfl_xor(acc[x], 32);
    }
    if (grp == 0) {
        bf16x8 self = *reinterpret_cast<const bf16x8*>(emb + (size_t)wid * 64 + q * 8);
        bf16x8 o;
#pragma unroll
        for (int x = 0; x < 8; ++x) o[x] = (short)f2bf(acc[x] + bf2f((unsigned short)self[x]));
        *reinterpret_cast<bf16x8*>(vbuf + (size_t)wid * 64 + q * 8) = o;
    }
}

// mlp-lite: zero LDS staging of weights/V -- MFMA fragments loaded directly from
// global (coalesced permuted wave reads, L2-resident weights). LDS only for the
// within-wave r exchange (9.2KB, rows padded to 72). NO __syncthreads at all:
// r exchange is within-wave (ds_write then ds_read, program order); embOut is
// stored per-wave from its own strip; f accumulated via per-wave global atomics.
// Tail-block NaN safety: vbuf padded; relu's fmaxf(x,0) washes NaN to 0 before
// anything reaches f; node<N zeroes tail softmax contributions.
__global__ __launch_bounds__(256) void mlp_kernel(
        const unsigned short* __restrict__ vbuf, unsigned short* __restrict__ emb_out,
        const unsigned short* __restrict__ whT, const unsigned short* __restrict__ wfpT,
        const float* __restrict__ bh, const float* __restrict__ bfp,
        float* __restrict__ f, int N) {
    __shared__ unsigned short sR[BM * 72];

    int tid = threadIdx.x;
    int base = blockIdx.x * BM;
    int lane = tid & 63, w = tid >> 6;
    int m16 = lane & 15, g = lane >> 4;
    int arow = w * 16 + m16;

    // A-fragments direct from vbuf (padded alloc: OOB rows read finite junk)
    const unsigned short* vrow = vbuf + (size_t)(base + arow) * 64;
    bf16x8 a0 = *reinterpret_cast<const bf16x8*>(vrow + g * 8);
    bf16x8 a1 = *reinterpret_cast<const bf16x8*>(vrow + 32 + g * 8);

    // ---- GEMM1: r = relu(V @ Wh + bh) ----
    f32x4 acc[4];
#pragma unroll
    for (int c = 0; c < 4; ++c) {
        bf16x8 b0 = *reinterpret_cast<const bf16x8*>(whT + (c * 16 + m16) * 64 + g * 8);
        bf16x8 b1 = *reinterpret_cast<const bf16x8*>(whT + (c * 16 + m16) * 64 + 32 + g * 8);
        f32x4 z = {0.f, 0.f, 0.f, 0.f};
        z = __builtin_amdgcn_mfma_f32_16x16x32_bf16(a0, b0, z, 0, 0, 0);
        z = __builtin_amdgcn_mfma_f32_16x16x32_bf16(a1, b1, z, 0, 0, 0);
        acc[c] = z;
    }
    // bias + relu -> own-wave strip of sR. C layout: row=(lane>>4)*4+reg, col=c*16+m16.
#pragma unroll
    for (int c = 0; c < 4; ++c) {
        float bias = bh[c * 16 + m16];
#pragma unroll
        for (int reg = 0; reg < 4; ++reg) {
            float rv = fmaxf(acc[c][reg] + bias, 0.f);  // fmax washes NaN -> 0
            sR[(w * 16 + g * 4 + reg) * 72 + c * 16 + m16] = f2bf(rv);
        }
    }

    // r A-fragments for GEMM2 (within-wave LDS dependency; no barrier needed)
    bf16x8 ra0 = *reinterpret_cast<const bf16x8*>(sR + arow * 72 + g * 8);
    bf16x8 ra1 = *reinterpret_cast<const bf16x8*>(sR + arow * 72 + 32 + g * 8);

    // store r -> embOut: each wave stores its OWN 16-row strip (2KB, coalesced)
#pragma unroll
    for (int it = 0; it < 2; ++it) {
        int lidx = w * 1024 + it * 512 + lane * 8;
        int row = lidx >> 6;
        if (base + row < N)
            *reinterpret_cast<bf16x8*>(emb_out + (size_t)base * 64 + lidx) =
                *reinterpret_cast<const bf16x8*>(sR + row * 72 + (lidx & 63));
    }

    // ---- GEMM2: z = r @ Wfp + bfp (16 x 128 per wave), B direct from global ----
    f32x4 z[8];
#pragma unroll
    for (int t = 0; t < 8; ++t) {
        bf16x8 b0 = *reinterpret_cast<const bf16x8*>(wfpT + (t * 16 + m16) * 64 + g * 8);
        bf16x8 b1 = *reinterpret_cast<const bf16x8*>(wfpT + (t * 16 + m16) * 64 + 32 + g * 8);
        f32x4 zz = {0.f, 0.f, 0.f, 0.f};
        zz = __builtin_amdgcn_mfma_f32_16x16x32_bf16(ra0, b0, zz, 0, 0, 0);
        zz = __builtin_amdgcn_mfma_f32_16x16x32_bf16(ra1, b1, zz, 0, 0, 0);
        float bias = bfp[t * 16 + m16];
#pragma unroll
        for (int reg = 0; reg < 4; ++reg) zz[reg] += bias;
        z[t] = zz;
    }

    // ---- softmax over 128 cols per node-row (rows live in 16-lane groups) ----
#pragma unroll
    for (int reg = 0; reg < 4; ++reg) {
        float mx = -1e30f;
#pragma unroll
        for (int t = 0; t < 8; ++t) mx = fmaxf(mx, z[t][reg]);
#pragma unroll
        for (int d = 1; d < 16; d <<= 1) mx = fmaxf(mx, __shfl_xor(mx, d));
        float s = 0.f;
#pragma unroll
        for (int t = 0; t < 8; ++t) {
            float p = __expf(z[t][reg] - mx);
            z[t][reg] = p;
            s += p;
        }
#pragma unroll
        for (int d = 1; d < 16; d <<= 1) s += __shfl_xor(s, d);
        int node = base + w * 16 + g * 4 + reg;
        float inv = (node < N) ? (1.f / s) : 0.f;
#pragma unroll
        for (int t = 0; t < 8; ++t) z[t][reg] *= inv;
    }
    // per-wave column sums -> global f atomics (128 adds/wave, ~400k total: ~2-4us)
#pragma unroll
    for (int t = 0; t < 8; ++t) {
        float v = z[t][0] + z[t][1] + z[t][2] + z[t][3];
        v += __shfl_xor(v, 16);
        v += __shfl_xor(v, 32);
        if (g == 0) unsafeAtomicAdd(&f[t * 16 + m16], v);
    }
}

__global__ void final_kernel(const float* __restrict__ f, const float* __restrict__ Wcl,
                             const float* __restrict__ bcl, float* __restrict__ out) {
    __shared__ float logits[10];
    int c = threadIdx.x;
    if (c < 10) {
        float acc = bcl[c];
        for (int l = 0; l < LFP; l++) acc = fmaf(f[l], Wcl[l * 10 + c], acc);
        logits[c] = acc;
    }
    __syncthreads();
    if (c == 0) {
        float m = -1e30f;
        for (int i = 0; i < 10; i++) m = fmaxf(m, logits[i]);
        float e[10], s = 0.f;
        for (int i = 0; i < 10; i++) { e[i] = __expf(logits[i] - m); s += e[i]; }
        for (int i = 0; i < 10; i++) out[i] = e[i] / s;
    }
}

extern "C" void kernel_launch(void* const* d_in, const int* in_sizes, int n_in,
                              void* d_out, int out_size, void* d_ws, size_t ws_size,
                              hipStream_t stream) {
    const int* feat = (const int*)d_in[0];
    const int* esrc = (const int*)d_in[1];
    const int* edst = (const int*)d_in[2];
    const float* table = (const float*)d_in[3];
    const float* Wh = (const float*)d_in[4];
    const float* bh = (const float*)d_in[5];
    const float* Wfp = (const float*)d_in[6];
    const float* bfp = (const float*)d_in[7];
    const float* Wcl = (const float*)d_in[8];
    const float* bcl = (const float*)d_in[9];
    float* out = (float*)d_out;
    int N = in_sizes[0];
    int nE = in_sizes[1];

    char* ws = (char*)d_ws;
    size_t off = 0;
    auto alloc = [&](size_t bytes) { void* p = ws + off; off += (bytes + 63) & ~(size_t)63; return p; };
    unsigned short* embA = (unsigned short*)alloc((size_t)N * 64 * 2);
    unsigned short* vbuf = (unsigned short*)alloc((size_t)(N + BM) * 64 * 2);  // +BM pad rows for tail-block reads
    float* f           = (float*)alloc(LFP * 4);
    unsigned short* whT  = (unsigned short*)alloc(RROUNDS * 64 * 64 * 2);
    unsigned short* wfpT = (unsigned short*)alloc(RROUNDS * 128 * 64 * 2);
    int* cnt    = (int*)alloc((size_t)N * 4);
    int* rp     = (int*)alloc(((size_t)N + 1) * 4);
    int* cursor = (int*)alloc((size_t)N * 4);
    int* bsum   = (int*)alloc(((size_t)(N + SCAN_B - 1) / SCAN_B) * 4);
    int* csr    = (int*)alloc((size_t)nE * 4);

    int nblk_scan = (N + SCAN_B - 1) / SCAN_B;

    // CSR build (rebuilt every call — deterministic, no cross-call state)
    hipMemsetAsync(cnt, 0, (size_t)N * 4, stream);
    hist_kernel<<<(nE + 255) / 256, 256, 0, stream>>>(edst, cnt, nE);
    scan1_kernel<<<nblk_scan, 256, 0, stream>>>(cnt, rp, bsum, N);
    scan3_kernel<<<(N + 256) / 256, 256, 0, stream>>>(rp, bsum, cursor, nblk_scan, N, nE);
    fill_kernel<<<(nE + 255) / 256, 256, 0, stream>>>(esrc, edst, cursor, csr, nE);

    prep_kernel<<<192, 256, 0, stream>>>(Wh, Wfp, whT, wfpT);
    init_kernel<<<(N * FDIM + 255) / 256, 256, 0, stream>>>(feat, table, embA, f, N);

    for (int r = 0; r < RROUNDS; ++r) {
        gather_kernel<<<(N * 64 + 255) / 256, 256, 0, stream>>>(embA, rp, csr, vbuf, N);
        mlp_kernel<<<(N + BM - 1) / BM, 256, 0, stream>>>(
            vbuf, embA, whT + (size_t)r * 4096, wfpT + (size_t)r * 8192,
            bh + (size_t)r * FDIM, bfp + (size_t)r * LFP, f, N);
    }

    final_kernel<<<1, 64, 0, stream>>>(f, Wcl, bcl, out);
}

// Round 8
// 346.754 us; speedup vs baseline: 1.6256x; 1.6256x over previous
//
#include <hip/hip_runtime.h>
#include <hip/hip_bf16.h>

#define FDIM 64
#define LFP 128
#define RROUNDS 4
#define BM 64      // nodes per block in mlp kernel
#define SCAN_B 1024
#define RED_B 16   // reduce_kernel blocks

typedef __attribute__((ext_vector_type(8))) short bf16x8;
typedef __attribute__((ext_vector_type(4))) float f32x4;

__device__ __forceinline__ float bf2f(unsigned short u) {
    unsigned int x = ((unsigned int)u) << 16;
    float f;
    __builtin_memcpy(&f, &x, 4);
    return f;
}
__device__ __forceinline__ unsigned short f2bf(float x) {
    unsigned int u;
    __builtin_memcpy(&u, &x, 4);
    unsigned int r = (u + 0x7fffu + ((u >> 16) & 1u)) >> 16;  // RNE
    return (unsigned short)r;
}

// ---------------- CSR build ----------------
__global__ void hist_kernel(const int* __restrict__ dst, int* __restrict__ cnt, int nE) {
    int e = blockIdx.x * blockDim.x + threadIdx.x;
    if (e < nE) atomicAdd(&cnt[dst[e]], 1);
}

__global__ __launch_bounds__(256) void scan1_kernel(const int* __restrict__ cnt,
                                                    int* __restrict__ rp, int* __restrict__ bsum, int n) {
    __shared__ int s[256];
    int t = threadIdx.x;
    int base = blockIdx.x * SCAN_B;
    int v[4], sum = 0;
#pragma unroll
    for (int i = 0; i < 4; i++) {
        int idx = base + t * 4 + i;
        v[i] = (idx < n) ? cnt[idx] : 0;
        sum += v[i];
    }
    s[t] = sum;
    __syncthreads();
    for (int d = 1; d < 256; d <<= 1) {
        int x = (t >= d) ? s[t - d] : 0;
        __syncthreads();
        s[t] += x;
        __syncthreads();
    }
    int excl = (t > 0) ? s[t - 1] : 0;
#pragma unroll
    for (int i = 0; i < 4; i++) {
        int idx = base + t * 4 + i;
        if (idx < n) { rp[idx] = excl; excl += v[i]; }
    }
    if (t == 255) bsum[blockIdx.x] = s[255];
}

// scan3 with scan2 merged: each block redoes the (nb<=64) block-sum wave scan.
__global__ __launch_bounds__(256) void scan3_kernel(int* __restrict__ rp, const int* __restrict__ bsum,
                                                    int* __restrict__ cursor, int nb, int n, int nE) {
    __shared__ int sB[64];
    int t = threadIdx.x;
    if (t < 64) {
        int v = (t < nb) ? bsum[t] : 0;
#pragma unroll
        for (int d = 1; d < 64; d <<= 1) {
            int x = __shfl_up(v, d);
            if (t >= d) v += x;
        }
        int e = __shfl_up(v, 1);
        if (t == 0) e = 0;
        sB[t] = e;
    }
    __syncthreads();
    int idx = blockIdx.x * blockDim.x + t;
    if (idx < n) {
        int v = rp[idx] + sB[idx / SCAN_B];
        rp[idx] = v;
        cursor[idx] = v;
    }
    if (idx == n) rp[n] = nE;
}

__global__ void fill_kernel(const int* __restrict__ src, const int* __restrict__ dst,
                            int* __restrict__ cursor, int* __restrict__ csr, int nE) {
    int e = blockIdx.x * blockDim.x + threadIdx.x;
    if (e < nE) {
        int p = atomicAdd(&cursor[dst[e]], 1);
        csr[p] = src[e];
    }
}

// ---------------- pipeline ----------------
__global__ void prep_kernel(const float* __restrict__ Wh, const float* __restrict__ Wfp,
                            unsigned short* __restrict__ whT, unsigned short* __restrict__ wfpT) {
    int o = blockIdx.x * blockDim.x + threadIdx.x;
    if (o < RROUNDS * FDIM * FDIM) {
        int r = o >> 12, rem = o & 4095, j = rem >> 6, k = rem & 63;
        whT[o] = f2bf(Wh[r * 4096 + k * 64 + j]);
    } else {
        int o2 = o - RROUNDS * FDIM * FDIM;
        int r = o2 >> 13, rem = o2 & 8191, l = rem >> 6, k = rem & 63;
        wfpT[o2] = f2bf(Wfp[r * 8192 + k * 128 + l]);
    }
}

__global__ void init_kernel(const int* __restrict__ feat, const float* __restrict__ table,
                            unsigned short* __restrict__ emb, int n) {
    int gid = blockIdx.x * blockDim.x + threadIdx.x;
    if (gid < n * FDIM) {
        int node = gid >> 6;
        int d = gid & 63;
        emb[gid] = f2bf(table[feat[node] * FDIM + d]);
    }
}

// one wave per node: v[n] = emb[n] + sum_{nbr} emb[nbr], via CSR.
// 8 neighbors/iter x 8 lanes x bf16x8(16B) = one full 128B emb row per neighbor.
__global__ __launch_bounds__(256) void gather_kernel(
        const unsigned short* __restrict__ emb, const int* __restrict__ rp,
        const int* __restrict__ csr, unsigned short* __restrict__ vbuf, int N) {
    int wid = (int)((blockIdx.x * 256 + threadIdx.x) >> 6);
    int lane = threadIdx.x & 63;
    if (wid >= N) return;
    int start = rp[wid], end = rp[wid + 1];
    int grp = lane >> 3, q = lane & 7;
    float acc[8] = {0.f, 0.f, 0.f, 0.f, 0.f, 0.f, 0.f, 0.f};
    for (int j = start + grp; j < end; j += 8) {
        int nb = csr[j];
        bf16x8 u = *reinterpret_cast<const bf16x8*>(emb + (size_t)nb * 64 + q * 8);
#pragma unroll
        for (int x = 0; x < 8; ++x) acc[x] += bf2f((unsigned short)u[x]);
    }
#pragma unroll
    for (int x = 0; x < 8; ++x) {
        acc[x] += __shfl_xor(acc[x], 8);
        acc[x] += __shfl_xor(acc[x], 16);
        acc[x] += __shfl_xor(acc[x], 32);
    }
    if (grp == 0) {
        bf16x8 self = *reinterpret_cast<const bf16x8*>(emb + (size_t)wid * 64 + q * 8);
        bf16x8 o;
#pragma unroll
        for (int x = 0; x < 8; ++x) o[x] = (short)f2bf(acc[x] + bf2f((unsigned short)self[x]));
        *reinterpret_cast<bf16x8*>(vbuf + (size_t)wid * 64 + q * 8) = o;
    }
}

// mlp: MFMA fragments loaded directly from global (coalesced permuted wave reads,
// L2-resident weights). LDS: sR for within-wave r exchange + sFp wave slices.
// NO atomics anywhere: per-wave col sums -> sFp[w] -> block sum -> plain store
// to fpart slice. (Round-7 lesson: 400k contended global fp atomics to 8 cache
// lines gate wave retirement -> 89us; hierarchical reduce instead.)
__global__ __launch_bounds__(256) void mlp_kernel(
        const unsigned short* __restrict__ vbuf, unsigned short* __restrict__ emb_out,
        const unsigned short* __restrict__ whT, const unsigned short* __restrict__ wfpT,
        const float* __restrict__ bh, const float* __restrict__ bfp,
        float* __restrict__ fpart, int N) {
    __shared__ unsigned short sR[BM * 72];
    __shared__ float sFp[4][128];

    int tid = threadIdx.x;
    int base = blockIdx.x * BM;
    int lane = tid & 63, w = tid >> 6;
    int m16 = lane & 15, g = lane >> 4;
    int arow = w * 16 + m16;

    // A-fragments direct from vbuf (padded alloc: OOB rows read finite junk)
    const unsigned short* vrow = vbuf + (size_t)(base + arow) * 64;
    bf16x8 a0 = *reinterpret_cast<const bf16x8*>(vrow + g * 8);
    bf16x8 a1 = *reinterpret_cast<const bf16x8*>(vrow + 32 + g * 8);

    // ---- GEMM1: r = relu(V @ Wh + bh) ----
    f32x4 acc[4];
#pragma unroll
    for (int c = 0; c < 4; ++c) {
        bf16x8 b0 = *reinterpret_cast<const bf16x8*>(whT + (c * 16 + m16) * 64 + g * 8);
        bf16x8 b1 = *reinterpret_cast<const bf16x8*>(whT + (c * 16 + m16) * 64 + 32 + g * 8);
        f32x4 z = {0.f, 0.f, 0.f, 0.f};
        z = __builtin_amdgcn_mfma_f32_16x16x32_bf16(a0, b0, z, 0, 0, 0);
        z = __builtin_amdgcn_mfma_f32_16x16x32_bf16(a1, b1, z, 0, 0, 0);
        acc[c] = z;
    }
    // bias + relu -> own-wave strip of sR. C layout: row=(lane>>4)*4+reg, col=c*16+m16.
#pragma unroll
    for (int c = 0; c < 4; ++c) {
        float bias = bh[c * 16 + m16];
#pragma unroll
        for (int reg = 0; reg < 4; ++reg) {
            float rv = fmaxf(acc[c][reg] + bias, 0.f);  // fmax washes NaN -> 0
            sR[(w * 16 + g * 4 + reg) * 72 + c * 16 + m16] = f2bf(rv);
        }
    }

    // r A-fragments for GEMM2 (within-wave LDS dependency; no barrier needed)
    bf16x8 ra0 = *reinterpret_cast<const bf16x8*>(sR + arow * 72 + g * 8);
    bf16x8 ra1 = *reinterpret_cast<const bf16x8*>(sR + arow * 72 + 32 + g * 8);

    // store r -> embOut: each wave stores its OWN 16-row strip (2KB, coalesced)
#pragma unroll
    for (int it = 0; it < 2; ++it) {
        int lidx = w * 1024 + it * 512 + lane * 8;
        int row = lidx >> 6;
        if (base + row < N)
            *reinterpret_cast<bf16x8*>(emb_out + (size_t)base * 64 + lidx) =
                *reinterpret_cast<const bf16x8*>(sR + row * 72 + (lidx & 63));
    }

    // ---- GEMM2: z = r @ Wfp + bfp (16 x 128 per wave), B direct from global ----
    f32x4 z[8];
#pragma unroll
    for (int t = 0; t < 8; ++t) {
        bf16x8 b0 = *reinterpret_cast<const bf16x8*>(wfpT + (t * 16 + m16) * 64 + g * 8);
        bf16x8 b1 = *reinterpret_cast<const bf16x8*>(wfpT + (t * 16 + m16) * 64 + 32 + g * 8);
        f32x4 zz = {0.f, 0.f, 0.f, 0.f};
        zz = __builtin_amdgcn_mfma_f32_16x16x32_bf16(ra0, b0, zz, 0, 0, 0);
        zz = __builtin_amdgcn_mfma_f32_16x16x32_bf16(ra1, b1, zz, 0, 0, 0);
        float bias = bfp[t * 16 + m16];
#pragma unroll
        for (int reg = 0; reg < 4; ++reg) zz[reg] += bias;
        z[t] = zz;
    }

    // ---- softmax over 128 cols per node-row (rows live in 16-lane groups) ----
#pragma unroll
    for (int reg = 0; reg < 4; ++reg) {
        float mx = -1e30f;
#pragma unroll
        for (int t = 0; t < 8; ++t) mx = fmaxf(mx, z[t][reg]);
#pragma unroll
        for (int d = 1; d < 16; d <<= 1) mx = fmaxf(mx, __shfl_xor(mx, d));
        float s = 0.f;
#pragma unroll
        for (int t = 0; t < 8; ++t) {
            float p = __expf(z[t][reg] - mx);
            z[t][reg] = p;
            s += p;
        }
#pragma unroll
        for (int d = 1; d < 16; d <<= 1) s += __shfl_xor(s, d);
        int node = base + w * 16 + g * 4 + reg;
        float inv = (node < N) ? (1.f / s) : 0.f;
#pragma unroll
        for (int t = 0; t < 8; ++t) z[t][reg] *= inv;
    }
    // per-wave column sums -> own LDS slice (no atomics)
#pragma unroll
    for (int t = 0; t < 8; ++t) {
        float v = z[t][0] + z[t][1] + z[t][2] + z[t][3];
        v += __shfl_xor(v, 16);
        v += __shfl_xor(v, 32);
        if (g == 0) sFp[w][t * 16 + m16] = v;
    }
    __syncthreads();
    if (tid < 128) {
        float s = sFp[0][tid] + sFp[1][tid] + sFp[2][tid] + sFp[3][tid];
        fpart[(size_t)blockIdx.x * 128 + tid] = s;  // plain coalesced store
    }
}

// sum 128-wide slices: block bb reduces its slice range into fred[bb][128]
__global__ __launch_bounds__(128) void reduce_kernel(const float* __restrict__ fpart,
                                                     float* __restrict__ fred, int nslice) {
    int t = threadIdx.x, bb = blockIdx.x;
    int chunk = (nslice + RED_B - 1) / RED_B;
    int b0 = bb * chunk;
    int b1 = b0 + chunk; if (b1 > nslice) b1 = nslice;
    float acc = 0.f;
    for (int b = b0; b < b1; ++b) acc += fpart[(size_t)b * 128 + t];
    fred[bb * 128 + t] = acc;
}

__global__ __launch_bounds__(128) void final_kernel(const float* __restrict__ fred,
                                                    const float* __restrict__ Wcl,
                                                    const float* __restrict__ bcl,
                                                    float* __restrict__ out) {
    __shared__ float sf[128];
    __shared__ float logits[10];
    int t = threadIdx.x;
    float a = 0.f;
#pragma unroll
    for (int bb = 0; bb < RED_B; ++bb) a += fred[bb * 128 + t];
    sf[t] = a;
    __syncthreads();
    if (t < 10) {
        float acc = bcl[t];
        for (int l = 0; l < LFP; l++) acc = fmaf(sf[l], Wcl[l * 10 + t], acc);
        logits[t] = acc;
    }
    __syncthreads();
    if (t == 0) {
        float m = -1e30f;
        for (int i = 0; i < 10; i++) m = fmaxf(m, logits[i]);
        float e[10], s = 0.f;
        for (int i = 0; i < 10; i++) { e[i] = __expf(logits[i] - m); s += e[i]; }
        for (int i = 0; i < 10; i++) out[i] = e[i] / s;
    }
}

extern "C" void kernel_launch(void* const* d_in, const int* in_sizes, int n_in,
                              void* d_out, int out_size, void* d_ws, size_t ws_size,
                              hipStream_t stream) {
    const int* feat = (const int*)d_in[0];
    const int* esrc = (const int*)d_in[1];
    const int* edst = (const int*)d_in[2];
    const float* table = (const float*)d_in[3];
    const float* Wh = (const float*)d_in[4];
    const float* bh = (const float*)d_in[5];
    const float* Wfp = (const float*)d_in[6];
    const float* bfp = (const float*)d_in[7];
    const float* Wcl = (const float*)d_in[8];
    const float* bcl = (const float*)d_in[9];
    float* out = (float*)d_out;
    int N = in_sizes[0];
    int nE = in_sizes[1];

    int nbm = (N + BM - 1) / BM;  // mlp blocks (782)

    char* ws = (char*)d_ws;
    size_t off = 0;
    auto alloc = [&](size_t bytes) { void* p = ws + off; off += (bytes + 63) & ~(size_t)63; return p; };
    unsigned short* embA = (unsigned short*)alloc((size_t)N * 64 * 2);
    unsigned short* vbuf = (unsigned short*)alloc((size_t)(N + BM) * 64 * 2);  // +pad rows for tail-block reads
    unsigned short* whT  = (unsigned short*)alloc(RROUNDS * 64 * 64 * 2);
    unsigned short* wfpT = (unsigned short*)alloc(RROUNDS * 128 * 64 * 2);
    float* fpart = (float*)alloc((size_t)RROUNDS * nbm * 128 * 4);  // per-block round slices
    float* fred  = (float*)alloc(RED_B * 128 * 4);
    int* cnt    = (int*)alloc((size_t)N * 4);
    int* rp     = (int*)alloc(((size_t)N + 1) * 4);
    int* cursor = (int*)alloc((size_t)N * 4);
    int* bsum   = (int*)alloc(((size_t)(N + SCAN_B - 1) / SCAN_B) * 4);
    int* csr    = (int*)alloc((size_t)nE * 4);

    int nblk_scan = (N + SCAN_B - 1) / SCAN_B;

    // CSR build (rebuilt every call — deterministic content, no cross-call state)
    hipMemsetAsync(cnt, 0, (size_t)N * 4, stream);
    hist_kernel<<<(nE + 255) / 256, 256, 0, stream>>>(edst, cnt, nE);
    scan1_kernel<<<nblk_scan, 256, 0, stream>>>(cnt, rp, bsum, N);
    scan3_kernel<<<(N + 256) / 256, 256, 0, stream>>>(rp, bsum, cursor, nblk_scan, N, nE);
    fill_kernel<<<(nE + 255) / 256, 256, 0, stream>>>(esrc, edst, cursor, csr, nE);

    prep_kernel<<<192, 256, 0, stream>>>(Wh, Wfp, whT, wfpT);
    init_kernel<<<(N * FDIM + 255) / 256, 256, 0, stream>>>(feat, table, embA, N);

    for (int r = 0; r < RROUNDS; ++r) {
        gather_kernel<<<(N * 64 + 255) / 256, 256, 0, stream>>>(embA, rp, csr, vbuf, N);
        mlp_kernel<<<nbm, 256, 0, stream>>>(
            vbuf, embA, whT + (size_t)r * 4096, wfpT + (size_t)r * 8192,
            bh + (size_t)r * FDIM, bfp + (size_t)r * LFP,
            fpart + (size_t)r * nbm * 128, N);
    }

    reduce_kernel<<<RED_B, 128, 0, stream>>>(fpart, fred, RROUNDS * nbm);
    final_kernel<<<1, 128, 0, stream>>>(fred, Wcl, bcl, out);
}

// Round 9
// 293.884 us; speedup vs baseline: 1.9181x; 1.1799x over previous
//
#include <hip/hip_runtime.h>
#include <hip/hip_bf16.h>

#define FDIM 64
#define LFP 128
#define RROUNDS 4
#define BM 64       // nodes per block in mlp kernel
#define RED_B 16    // reduce_kernel blocks
#define PCHUNK 4096 // edges per partition block
#define CB 512      // nodes per coarse bucket
#define MAXB 10240  // max edges per coarse bucket (mean 8192, sigma ~90)

typedef __attribute__((ext_vector_type(8))) short bf16x8;
typedef __attribute__((ext_vector_type(4))) float f32x4;

__device__ __forceinline__ float bf2f(unsigned short u) {
    unsigned int x = ((unsigned int)u) << 16;
    float f;
    __builtin_memcpy(&f, &x, 4);
    return f;
}
__device__ __forceinline__ unsigned short f2bf(float x) {
    unsigned int u;
    __builtin_memcpy(&u, &x, 4);
    unsigned int r = (u + 0x7fffu + ((u >> 16) & 1u)) >> 16;  // RNE
    return (unsigned short)r;
}

// ---------------- CSR build: 2-level LDS bucket sort ----------------
// All output lines written once, coalesced, by a single block (round-8 lesson:
// random scattered 4B stores cost a full 64B HBM line each -> 52MB for 3.2MB).

// coarse histogram over nbc buckets (dst>>9), LDS-privatized
__global__ __launch_bounds__(256) void chist_kernel(const int* __restrict__ dst,
                                                    int* __restrict__ chist, int nE, int nbc) {
    __shared__ int scnt[128];
    int t = threadIdx.x;
    if (t < 128) scnt[t] = 0;
    __syncthreads();
    int c0 = blockIdx.x * PCHUNK;
#pragma unroll
    for (int k = 0; k < PCHUNK / 256; ++k) {
        int idx = c0 + k * 256 + t;
        if (idx < nE) atomicAdd(&scnt[dst[idx] >> 9], 1);
    }
    __syncthreads();
    if (t < nbc && scnt[t] > 0) atomicAdd(&chist[t], scnt[t]);
}

// exclusive scan of nbc (<=128) bucket counts -> cbase, ccursor; cbase[nbc]=nE
__global__ __launch_bounds__(128) void cscan_kernel(const int* __restrict__ chist,
                                                    int* __restrict__ cbase,
                                                    int* __restrict__ ccursor, int nbc, int nE) {
    __shared__ int s[128];
    int t = threadIdx.x;
    int v = (t < nbc) ? chist[t] : 0;
    s[t] = v;
    __syncthreads();
    for (int d = 1; d < 128; d <<= 1) {
        int x = (t >= d) ? s[t - d] : 0;
        __syncthreads();
        s[t] += x;
        __syncthreads();
    }
    int ex = s[t] - v;
    if (t < nbc) { cbase[t] = ex; ccursor[t] = ex; }
    if (t == 0) cbase[nbc] = nE;
}

// partition edges into coarse-bucket-ordered tmp[], packed (src<<9)|(dst&511).
// LDS staging + per-(block,bucket) bulk reservation -> coalesced run writes.
__global__ __launch_bounds__(256) void partition_kernel(
        const int* __restrict__ esrc, const int* __restrict__ edst,
        int* __restrict__ ccursor, int* __restrict__ tmp, int nE, int nbc) {
    __shared__ int scnt[128], sinc[128], sexc[128], sgbase[128], scur[128];
    __shared__ int sbuf[PCHUNK];
    __shared__ int starg[PCHUNK];
    int t = threadIdx.x;
    int c0 = blockIdx.x * PCHUNK;
    int cend = c0 + PCHUNK; if (cend > nE) cend = nE;

    if (t < 128) scnt[t] = 0;
    __syncthreads();
#pragma unroll
    for (int k = 0; k < PCHUNK / 256; ++k) {
        int idx = c0 + k * 256 + t;
        if (idx < cend) atomicAdd(&scnt[edst[idx] >> 9], 1);
    }
    __syncthreads();
    if (t < 128) sinc[t] = scnt[t];
    __syncthreads();
    for (int d = 1; d < 128; d <<= 1) {
        int x = (t >= d && t < 128) ? sinc[t - d] : 0;
        __syncthreads();
        if (t < 128) sinc[t] += x;
        __syncthreads();
    }
    if (t < 128) {
        int ex = sinc[t] - scnt[t];
        sexc[t] = ex;
        scur[t] = ex;
        sgbase[t] = (t < nbc && scnt[t] > 0) ? atomicAdd(&ccursor[t], scnt[t]) : 0;
    }
    __syncthreads();
#pragma unroll
    for (int k = 0; k < PCHUNK / 256; ++k) {
        int idx = c0 + k * 256 + t;
        if (idx < cend) {
            int s = esrc[idx], d = edst[idx];
            int b = d >> 9;
            int pos = atomicAdd(&scur[b], 1);
            sbuf[pos] = (s << 9) | (d & 511);
            starg[pos] = sgbase[b] + (pos - sexc[b]);
        }
    }
    __syncthreads();
    int cnt = cend - c0;
#pragma unroll
    for (int k = 0; k < PCHUNK / 256; ++k) {
        int li = k * 256 + t;
        if (li < cnt) tmp[starg[li]] = sbuf[li];
    }
}

// per-bucket fine counting sort -> csr16 (ushort srcs) + rp (free from prefix)
__global__ __launch_bounds__(256) void bsort_kernel(
        const int* __restrict__ cbase, const int* __restrict__ tmp,
        unsigned short* __restrict__ csr16, int* __restrict__ rp, int N, int nE) {
    __shared__ unsigned short ssrc[MAXB];
    __shared__ int pcnt[CB], pexc[CB], pcur[CB];
    __shared__ int ssum[256];
    int t = threadIdx.x;
    int b = blockIdx.x;
    int lo = cbase[b], hi = cbase[b + 1];

    pcnt[t] = 0; pcnt[t + 256] = 0;
    __syncthreads();
    for (int idx = lo + t; idx < hi; idx += 256)
        atomicAdd(&pcnt[tmp[idx] & 511], 1);
    __syncthreads();
    int a0 = pcnt[2 * t], a1 = pcnt[2 * t + 1];
    ssum[t] = a0 + a1;
    __syncthreads();
    for (int d = 1; d < 256; d <<= 1) {
        int x = (t >= d) ? ssum[t - d] : 0;
        __syncthreads();
        ssum[t] += x;
        __syncthreads();
    }
    int ex = ssum[t] - (a0 + a1);
    pexc[2 * t] = ex;       pcur[2 * t] = ex;
    pexc[2 * t + 1] = ex + a0; pcur[2 * t + 1] = ex + a0;
    __syncthreads();
    // rp for this bucket's nodes (includes zero-degree nodes)
#pragma unroll
    for (int i = t; i < CB; i += 256) {
        int node = b * CB + i;
        if (node < N) rp[node] = lo + pexc[i];
    }
    if (b == 0 && t == 0) rp[N] = nE;
    // ranked scatter into LDS, then coalesced burst write
    for (int idx = lo + t; idx < hi; idx += 256) {
        int e = tmp[idx];
        int pos = atomicAdd(&pcur[e & 511], 1);
        ssrc[pos] = (unsigned short)(e >> 9);
    }
    __syncthreads();
    int cnt = hi - lo;
    for (int li = t; li < cnt; li += 256) csr16[lo + li] = ssrc[li];
}

// ---------------- pipeline ----------------
__global__ void prep_kernel(const float* __restrict__ Wh, const float* __restrict__ Wfp,
                            unsigned short* __restrict__ whT, unsigned short* __restrict__ wfpT) {
    int o = blockIdx.x * blockDim.x + threadIdx.x;
    if (o < RROUNDS * FDIM * FDIM) {
        int r = o >> 12, rem = o & 4095, j = rem >> 6, k = rem & 63;
        whT[o] = f2bf(Wh[r * 4096 + k * 64 + j]);
    } else {
        int o2 = o - RROUNDS * FDIM * FDIM;
        int r = o2 >> 13, rem = o2 & 8191, l = rem >> 6, k = rem & 63;
        wfpT[o2] = f2bf(Wfp[r * 8192 + k * 128 + l]);
    }
}

__global__ void init_kernel(const int* __restrict__ feat, const float* __restrict__ table,
                            unsigned short* __restrict__ emb, int n) {
    int gid = blockIdx.x * blockDim.x + threadIdx.x;
    if (gid < n * FDIM) {
        int node = gid >> 6;
        int d = gid & 63;
        emb[gid] = f2bf(table[feat[node] * FDIM + d]);
    }
}

// one wave per node: v[n] = emb[n] + sum_{nbr} emb[nbr], via CSR (ushort srcs).
// 8 neighbors/iter x 8 lanes x bf16x8(16B) = one full 128B emb row per neighbor.
__global__ __launch_bounds__(256) void gather_kernel(
        const unsigned short* __restrict__ emb, const int* __restrict__ rp,
        const unsigned short* __restrict__ csr16, unsigned short* __restrict__ vbuf, int N) {
    int wid = (int)((blockIdx.x * 256 + threadIdx.x) >> 6);
    int lane = threadIdx.x & 63;
    if (wid >= N) return;
    int start = rp[wid], end = rp[wid + 1];
    int grp = lane >> 3, q = lane & 7;
    float acc[8] = {0.f, 0.f, 0.f, 0.f, 0.f, 0.f, 0.f, 0.f};
    for (int j = start + grp; j < end; j += 8) {
        int nb = csr16[j];
        bf16x8 u = *reinterpret_cast<const bf16x8*>(emb + (size_t)nb * 64 + q * 8);
#pragma unroll
        for (int x = 0; x < 8; ++x) acc[x] += bf2f((unsigned short)u[x]);
    }
#pragma unroll
    for (int x = 0; x < 8; ++x) {
        acc[x] += __shfl_xor(acc[x], 8);
        acc[x] += __shfl_xor(acc[x], 16);
        acc[x] += __shfl_xor(acc[x], 32);
    }
    if (grp == 0) {
        bf16x8 self = *reinterpret_cast<const bf16x8*>(emb + (size_t)wid * 64 + q * 8);
        bf16x8 o;
#pragma unroll
        for (int x = 0; x < 8; ++x) o[x] = (short)f2bf(acc[x] + bf2f((unsigned short)self[x]));
        *reinterpret_cast<bf16x8*>(vbuf + (size_t)wid * 64 + q * 8) = o;
    }
}

// mlp: MFMA fragments direct from global (L2-resident weights); LDS only for
// within-wave r exchange + block fingerprint slices. NO atomics (round-7 lesson).
__global__ __launch_bounds__(256) void mlp_kernel(
        const unsigned short* __restrict__ vbuf, unsigned short* __restrict__ emb_out,
        const unsigned short* __restrict__ whT, const unsigned short* __restrict__ wfpT,
        const float* __restrict__ bh, const float* __restrict__ bfp,
        float* __restrict__ fpart, int N) {
    __shared__ unsigned short sR[BM * 72];
    __shared__ float sFp[4][128];

    int tid = threadIdx.x;
    int base = blockIdx.x * BM;
    int lane = tid & 63, w = tid >> 6;
    int m16 = lane & 15, g = lane >> 4;
    int arow = w * 16 + m16;

    const unsigned short* vrow = vbuf + (size_t)(base + arow) * 64;
    bf16x8 a0 = *reinterpret_cast<const bf16x8*>(vrow + g * 8);
    bf16x8 a1 = *reinterpret_cast<const bf16x8*>(vrow + 32 + g * 8);

    // ---- GEMM1: r = relu(V @ Wh + bh) ----
    f32x4 acc[4];
#pragma unroll
    for (int c = 0; c < 4; ++c) {
        bf16x8 b0 = *reinterpret_cast<const bf16x8*>(whT + (c * 16 + m16) * 64 + g * 8);
        bf16x8 b1 = *reinterpret_cast<const bf16x8*>(whT + (c * 16 + m16) * 64 + 32 + g * 8);
        f32x4 z = {0.f, 0.f, 0.f, 0.f};
        z = __builtin_amdgcn_mfma_f32_16x16x32_bf16(a0, b0, z, 0, 0, 0);
        z = __builtin_amdgcn_mfma_f32_16x16x32_bf16(a1, b1, z, 0, 0, 0);
        acc[c] = z;
    }
    // C layout: row=(lane>>4)*4+reg, col=c*16+m16
#pragma unroll
    for (int c = 0; c < 4; ++c) {
        float bias = bh[c * 16 + m16];
#pragma unroll
        for (int reg = 0; reg < 4; ++reg) {
            float rv = fmaxf(acc[c][reg] + bias, 0.f);  // fmax washes NaN -> 0
            sR[(w * 16 + g * 4 + reg) * 72 + c * 16 + m16] = f2bf(rv);
        }
    }

    bf16x8 ra0 = *reinterpret_cast<const bf16x8*>(sR + arow * 72 + g * 8);
    bf16x8 ra1 = *reinterpret_cast<const bf16x8*>(sR + arow * 72 + 32 + g * 8);

    // store r -> embOut: each wave its OWN 16-row strip (within-wave dep only)
#pragma unroll
    for (int it = 0; it < 2; ++it) {
        int lidx = w * 1024 + it * 512 + lane * 8;
        int row = lidx >> 6;
        if (base + row < N)
            *reinterpret_cast<bf16x8*>(emb_out + (size_t)base * 64 + lidx) =
                *reinterpret_cast<const bf16x8*>(sR + row * 72 + (lidx & 63));
    }

    // ---- GEMM2: z = r @ Wfp + bfp (16 x 128 per wave) ----
    f32x4 z[8];
#pragma unroll
    for (int t = 0; t < 8; ++t) {
        bf16x8 b0 = *reinterpret_cast<const bf16x8*>(wfpT + (t * 16 + m16) * 64 + g * 8);
        bf16x8 b1 = *reinterpret_cast<const bf16x8*>(wfpT + (t * 16 + m16) * 64 + 32 + g * 8);
        f32x4 zz = {0.f, 0.f, 0.f, 0.f};
        zz = __builtin_amdgcn_mfma_f32_16x16x32_bf16(ra0, b0, zz, 0, 0, 0);
        zz = __builtin_amdgcn_mfma_f32_16x16x32_bf16(ra1, b1, zz, 0, 0, 0);
        float bias = bfp[t * 16 + m16];
#pragma unroll
        for (int reg = 0; reg < 4; ++reg) zz[reg] += bias;
        z[t] = zz;
    }

    // ---- softmax over 128 cols per node-row ----
#pragma unroll
    for (int reg = 0; reg < 4; ++reg) {
        float mx = -1e30f;
#pragma unroll
        for (int t = 0; t < 8; ++t) mx = fmaxf(mx, z[t][reg]);
#pragma unroll
        for (int d = 1; d < 16; d <<= 1) mx = fmaxf(mx, __shfl_xor(mx, d));
        float s = 0.f;
#pragma unroll
        for (int t = 0; t < 8; ++t) {
            float p = __expf(z[t][reg] - mx);
            z[t][reg] = p;
            s += p;
        }
#pragma unroll
        for (int d = 1; d < 16; d <<= 1) s += __shfl_xor(s, d);
        int node = base + w * 16 + g * 4 + reg;
        float inv = (node < N) ? (1.f / s) : 0.f;
#pragma unroll
        for (int t = 0; t < 8; ++t) z[t][reg] *= inv;
    }
    // per-wave column sums -> LDS slices -> one plain store per block
#pragma unroll
    for (int t = 0; t < 8; ++t) {
        float v = z[t][0] + z[t][1] + z[t][2] + z[t][3];
        v += __shfl_xor(v, 16);
        v += __shfl_xor(v, 32);
        if (g == 0) sFp[w][t * 16 + m16] = v;
    }
    __syncthreads();
    if (tid < 128) {
        float s = sFp[0][tid] + sFp[1][tid] + sFp[2][tid] + sFp[3][tid];
        fpart[(size_t)blockIdx.x * 128 + tid] = s;
    }
}

__global__ __launch_bounds__(128) void reduce_kernel(const float* __restrict__ fpart,
                                                     float* __restrict__ fred, int nslice) {
    int t = threadIdx.x, bb = blockIdx.x;
    int chunk = (nslice + RED_B - 1) / RED_B;
    int b0 = bb * chunk;
    int b1 = b0 + chunk; if (b1 > nslice) b1 = nslice;
    float acc = 0.f;
    for (int b = b0; b < b1; ++b) acc += fpart[(size_t)b * 128 + t];
    fred[bb * 128 + t] = acc;
}

__global__ __launch_bounds__(128) void final_kernel(const float* __restrict__ fred,
                                                    const float* __restrict__ Wcl,
                                                    const float* __restrict__ bcl,
                                                    float* __restrict__ out) {
    __shared__ float sf[128];
    __shared__ float logits[10];
    int t = threadIdx.x;
    float a = 0.f;
#pragma unroll
    for (int bb = 0; bb < RED_B; ++bb) a += fred[bb * 128 + t];
    sf[t] = a;
    __syncthreads();
    if (t < 10) {
        float acc = bcl[t];
        for (int l = 0; l < LFP; l++) acc = fmaf(sf[l], Wcl[l * 10 + t], acc);
        logits[t] = acc;
    }
    __syncthreads();
    if (t == 0) {
        float m = -1e30f;
        for (int i = 0; i < 10; i++) m = fmaxf(m, logits[i]);
        float e[10], s = 0.f;
        for (int i = 0; i < 10; i++) { e[i] = __expf(logits[i] - m); s += e[i]; }
        for (int i = 0; i < 10; i++) out[i] = e[i] / s;
    }
}

extern "C" void kernel_launch(void* const* d_in, const int* in_sizes, int n_in,
                              void* d_out, int out_size, void* d_ws, size_t ws_size,
                              hipStream_t stream) {
    const int* feat = (const int*)d_in[0];
    const int* esrc = (const int*)d_in[1];
    const int* edst = (const int*)d_in[2];
    const float* table = (const float*)d_in[3];
    const float* Wh = (const float*)d_in[4];
    const float* bh = (const float*)d_in[5];
    const float* Wfp = (const float*)d_in[6];
    const float* bfp = (const float*)d_in[7];
    const float* Wcl = (const float*)d_in[8];
    const float* bcl = (const float*)d_in[9];
    float* out = (float*)d_out;
    int N = in_sizes[0];
    int nE = in_sizes[1];

    int nbm = (N + BM - 1) / BM;          // mlp blocks
    int nbc = (N + CB - 1) / CB;          // coarse buckets (98)
    int nbp = (nE + PCHUNK - 1) / PCHUNK; // partition blocks (196)

    char* ws = (char*)d_ws;
    size_t off = 0;
    auto alloc = [&](size_t bytes) { void* p = ws + off; off += (bytes + 63) & ~(size_t)63; return p; };
    unsigned short* embA = (unsigned short*)alloc((size_t)N * 64 * 2);
    unsigned short* vbuf = (unsigned short*)alloc((size_t)(N + BM) * 64 * 2);  // +pad for tail reads
    unsigned short* whT  = (unsigned short*)alloc(RROUNDS * 64 * 64 * 2);
    unsigned short* wfpT = (unsigned short*)alloc(RROUNDS * 128 * 64 * 2);
    float* fpart = (float*)alloc((size_t)RROUNDS * nbm * 128 * 4);
    float* fred  = (float*)alloc(RED_B * 128 * 4);
    int* chist   = (int*)alloc(128 * 4);
    int* cbase   = (int*)alloc(129 * 4);
    int* ccursor = (int*)alloc(128 * 4);
    int* rp      = (int*)alloc(((size_t)N + 1) * 4);
    int* tmp     = (int*)alloc((size_t)nE * 4);
    unsigned short* csr16 = (unsigned short*)alloc((size_t)nE * 2);

    // ---- CSR build (2-level bucket sort; rebuilt every call) ----
    hipMemsetAsync(chist, 0, 128 * 4, stream);
    chist_kernel<<<nbp, 256, 0, stream>>>(edst, chist, nE, nbc);
    cscan_kernel<<<1, 128, 0, stream>>>(chist, cbase, ccursor, nbc, nE);
    partition_kernel<<<nbp, 256, 0, stream>>>(esrc, edst, ccursor, tmp, nE, nbc);
    bsort_kernel<<<nbc, 256, 0, stream>>>(cbase, tmp, csr16, rp, N, nE);

    prep_kernel<<<192, 256, 0, stream>>>(Wh, Wfp, whT, wfpT);
    init_kernel<<<(N * FDIM + 255) / 256, 256, 0, stream>>>(feat, table, embA, N);

    for (int r = 0; r < RROUNDS; ++r) {
        gather_kernel<<<(N * 64 + 255) / 256, 256, 0, stream>>>(embA, rp, csr16, vbuf, N);
        mlp_kernel<<<nbm, 256, 0, stream>>>(
            vbuf, embA, whT + (size_t)r * 4096, wfpT + (size_t)r * 8192,
            bh + (size_t)r * FDIM, bfp + (size_t)r * LFP,
            fpart + (size_t)r * nbm * 128, N);
    }

    reduce_kernel<<<RED_B, 128, 0, stream>>>(fpart, fred, RROUNDS * nbm);
    final_kernel<<<1, 128, 0, stream>>>(fred, Wcl, bcl, out);
}

// Round 10
// 252.727 us; speedup vs baseline: 2.2304x; 1.1629x over previous
//
#include <hip/hip_runtime.h>
#include <hip/hip_bf16.h>

#define FDIM 64
#define LFP 128
#define RROUNDS 4
#define BM 64       // nodes per block in mlp kernel
#define PCHUNK 4096 // edges per partition block
#define CB 512      // nodes per coarse bucket
#define MAXB 10240  // max edges per coarse bucket (mean 8192)
#define RSL 32      // slices per reduce1 block

typedef __attribute__((ext_vector_type(8))) short bf16x8;
typedef __attribute__((ext_vector_type(4))) float f32x4;

__device__ __forceinline__ float bf2f(unsigned short u) {
    unsigned int x = ((unsigned int)u) << 16;
    float f;
    __builtin_memcpy(&f, &x, 4);
    return f;
}
__device__ __forceinline__ unsigned short f2bf(float x) {
    unsigned int u;
    __builtin_memcpy(&u, &x, 4);
    unsigned int r = (u + 0x7fffu + ((u >> 16) & 1u)) >> 16;  // RNE
    return (unsigned short)r;
}

// ---------------- CSR build: 2-level LDS bucket sort ----------------
__global__ __launch_bounds__(256) void chist_kernel(const int* __restrict__ dst,
                                                    int* __restrict__ chist, int nE, int nbc) {
    __shared__ int scnt[128];
    int t = threadIdx.x;
    if (t < 128) scnt[t] = 0;
    __syncthreads();
    int c0 = blockIdx.x * PCHUNK;
#pragma unroll
    for (int k = 0; k < PCHUNK / 256; ++k) {
        int idx = c0 + k * 256 + t;
        if (idx < nE) atomicAdd(&scnt[dst[idx] >> 9], 1);
    }
    __syncthreads();
    if (t < nbc && scnt[t] > 0) atomicAdd(&chist[t], scnt[t]);
}

__global__ __launch_bounds__(128) void cscan_kernel(const int* __restrict__ chist,
                                                    int* __restrict__ cbase,
                                                    int* __restrict__ ccursor, int nbc, int nE) {
    __shared__ int s[128];
    int t = threadIdx.x;
    int v = (t < nbc) ? chist[t] : 0;
    s[t] = v;
    __syncthreads();
    for (int d = 1; d < 128; d <<= 1) {
        int x = (t >= d) ? s[t - d] : 0;
        __syncthreads();
        s[t] += x;
        __syncthreads();
    }
    int ex = s[t] - v;
    if (t < nbc) { cbase[t] = ex; ccursor[t] = ex; }
    if (t == 0) cbase[nbc] = nE;
}

__global__ __launch_bounds__(256) void partition_kernel(
        const int* __restrict__ esrc, const int* __restrict__ edst,
        int* __restrict__ ccursor, int* __restrict__ tmp, int nE, int nbc) {
    __shared__ int scnt[128], sinc[128], sexc[128], sgbase[128], scur[128];
    __shared__ int sbuf[PCHUNK];
    __shared__ int starg[PCHUNK];
    int t = threadIdx.x;
    int c0 = blockIdx.x * PCHUNK;
    int cend = c0 + PCHUNK; if (cend > nE) cend = nE;

    if (t < 128) scnt[t] = 0;
    __syncthreads();
#pragma unroll
    for (int k = 0; k < PCHUNK / 256; ++k) {
        int idx = c0 + k * 256 + t;
        if (idx < cend) atomicAdd(&scnt[edst[idx] >> 9], 1);
    }
    __syncthreads();
    if (t < 128) sinc[t] = scnt[t];
    __syncthreads();
    for (int d = 1; d < 128; d <<= 1) {
        int x = (t >= d && t < 128) ? sinc[t - d] : 0;
        __syncthreads();
        if (t < 128) sinc[t] += x;
        __syncthreads();
    }
    if (t < 128) {
        int ex = sinc[t] - scnt[t];
        sexc[t] = ex;
        scur[t] = ex;
        sgbase[t] = (t < nbc && scnt[t] > 0) ? atomicAdd(&ccursor[t], scnt[t]) : 0;
    }
    __syncthreads();
#pragma unroll
    for (int k = 0; k < PCHUNK / 256; ++k) {
        int idx = c0 + k * 256 + t;
        if (idx < cend) {
            int s = esrc[idx], d = edst[idx];
            int b = d >> 9;
            int pos = atomicAdd(&scur[b], 1);
            sbuf[pos] = (s << 9) | (d & 511);
            starg[pos] = sgbase[b] + (pos - sexc[b]);
        }
    }
    __syncthreads();
    int cnt = cend - c0;
#pragma unroll
    for (int k = 0; k < PCHUNK / 256; ++k) {
        int li = k * 256 + t;
        if (li < cnt) tmp[starg[li]] = sbuf[li];
    }
}

__global__ __launch_bounds__(256) void bsort_kernel(
        const int* __restrict__ cbase, const int* __restrict__ tmp,
        unsigned short* __restrict__ csr16, int* __restrict__ rp, int N, int nE) {
    __shared__ unsigned short ssrc[MAXB];
    __shared__ int pcnt[CB], pexc[CB], pcur[CB];
    __shared__ int ssum[256];
    int t = threadIdx.x;
    int b = blockIdx.x;
    int lo = cbase[b], hi = cbase[b + 1];

    pcnt[t] = 0; pcnt[t + 256] = 0;
    __syncthreads();
    for (int idx = lo + t; idx < hi; idx += 256)
        atomicAdd(&pcnt[tmp[idx] & 511], 1);
    __syncthreads();
    int a0 = pcnt[2 * t], a1 = pcnt[2 * t + 1];
    ssum[t] = a0 + a1;
    __syncthreads();
    for (int d = 1; d < 256; d <<= 1) {
        int x = (t >= d) ? ssum[t - d] : 0;
        __syncthreads();
        ssum[t] += x;
        __syncthreads();
    }
    int ex = ssum[t] - (a0 + a1);
    pexc[2 * t] = ex;          pcur[2 * t] = ex;
    pexc[2 * t + 1] = ex + a0; pcur[2 * t + 1] = ex + a0;
    __syncthreads();
#pragma unroll
    for (int i = t; i < CB; i += 256) {
        int node = b * CB + i;
        if (node < N) rp[node] = lo + pexc[i];
    }
    if (b == 0 && t == 0) rp[N] = nE;
    for (int idx = lo + t; idx < hi; idx += 256) {
        int e = tmp[idx];
        int pos = atomicAdd(&pcur[e & 511], 1);
        ssrc[pos] = (unsigned short)(e >> 9);
    }
    __syncthreads();
    int cnt = hi - lo;
    for (int li = t; li < cnt; li += 256) csr16[lo + li] = ssrc[li];
}

// ---------------- pipeline ----------------
__global__ void prep_kernel(const float* __restrict__ Wh, const float* __restrict__ Wfp,
                            unsigned short* __restrict__ whT, unsigned short* __restrict__ wfpT) {
    int o = blockIdx.x * blockDim.x + threadIdx.x;
    if (o < RROUNDS * FDIM * FDIM) {
        int r = o >> 12, rem = o & 4095, j = rem >> 6, k = rem & 63;
        whT[o] = f2bf(Wh[r * 4096 + k * 64 + j]);
    } else {
        int o2 = o - RROUNDS * FDIM * FDIM;
        int r = o2 >> 13, rem = o2 & 8191, l = rem >> 6, k = rem & 63;
        wfpT[o2] = f2bf(Wfp[r * 8192 + k * 128 + l]);
    }
}

__global__ void init_kernel(const int* __restrict__ feat, const float* __restrict__ table,
                            unsigned short* __restrict__ emb, int n) {
    int gid = blockIdx.x * blockDim.x + threadIdx.x;
    if (gid < n * FDIM) {
        int node = gid >> 6;
        int d = gid & 63;
        emb[gid] = f2bf(table[feat[node] * FDIM + d]);
    }
}

__global__ __launch_bounds__(256) void gather_kernel(
        const unsigned short* __restrict__ emb, const int* __restrict__ rp,
        const unsigned short* __restrict__ csr16, unsigned short* __restrict__ vbuf, int N) {
    int wid = (int)((blockIdx.x * 256 + threadIdx.x) >> 6);
    int lane = threadIdx.x & 63;
    if (wid >= N) return;
    int start = rp[wid], end = rp[wid + 1];
    int grp = lane >> 3, q = lane & 7;
    float acc[8] = {0.f, 0.f, 0.f, 0.f, 0.f, 0.f, 0.f, 0.f};
    for (int j = start + grp; j < end; j += 8) {
        int nb = csr16[j];
        bf16x8 u = *reinterpret_cast<const bf16x8*>(emb + (size_t)nb * 64 + q * 8);
#pragma unroll
        for (int x = 0; x < 8; ++x) acc[x] += bf2f((unsigned short)u[x]);
    }
#pragma unroll
    for (int x = 0; x < 8; ++x) {
        acc[x] += __shfl_xor(acc[x], 8);
        acc[x] += __shfl_xor(acc[x], 16);
        acc[x] += __shfl_xor(acc[x], 32);
    }
    if (grp == 0) {
        bf16x8 self = *reinterpret_cast<const bf16x8*>(emb + (size_t)wid * 64 + q * 8);
        bf16x8 o;
#pragma unroll
        for (int x = 0; x < 8; ++x) o[x] = (short)f2bf(acc[x] + bf2f((unsigned short)self[x]));
        *reinterpret_cast<bf16x8*>(vbuf + (size_t)wid * 64 + q * 8) = o;
    }
}

__global__ __launch_bounds__(256) void mlp_kernel(
        const unsigned short* __restrict__ vbuf, unsigned short* __restrict__ emb_out,
        const unsigned short* __restrict__ whT, const unsigned short* __restrict__ wfpT,
        const float* __restrict__ bh, const float* __restrict__ bfp,
        float* __restrict__ fpart, int N) {
    __shared__ unsigned short sR[BM * 72];
    __shared__ float sFp[4][128];

    int tid = threadIdx.x;
    int base = blockIdx.x * BM;
    int lane = tid & 63, w = tid >> 6;
    int m16 = lane & 15, g = lane >> 4;
    int arow = w * 16 + m16;

    const unsigned short* vrow = vbuf + (size_t)(base + arow) * 64;
    bf16x8 a0 = *reinterpret_cast<const bf16x8*>(vrow + g * 8);
    bf16x8 a1 = *reinterpret_cast<const bf16x8*>(vrow + 32 + g * 8);

    f32x4 acc[4];
#pragma unroll
    for (int c = 0; c < 4; ++c) {
        bf16x8 b0 = *reinterpret_cast<const bf16x8*>(whT + (c * 16 + m16) * 64 + g * 8);
        bf16x8 b1 = *reinterpret_cast<const bf16x8*>(whT + (c * 16 + m16) * 64 + 32 + g * 8);
        f32x4 z = {0.f, 0.f, 0.f, 0.f};
        z = __builtin_amdgcn_mfma_f32_16x16x32_bf16(a0, b0, z, 0, 0, 0);
        z = __builtin_amdgcn_mfma_f32_16x16x32_bf16(a1, b1, z, 0, 0, 0);
        acc[c] = z;
    }
#pragma unroll
    for (int c = 0; c < 4; ++c) {
        float bias = bh[c * 16 + m16];
#pragma unroll
        for (int reg = 0; reg < 4; ++reg) {
            float rv = fmaxf(acc[c][reg] + bias, 0.f);
            sR[(w * 16 + g * 4 + reg) * 72 + c * 16 + m16] = f2bf(rv);
        }
    }

    bf16x8 ra0 = *reinterpret_cast<const bf16x8*>(sR + arow * 72 + g * 8);
    bf16x8 ra1 = *reinterpret_cast<const bf16x8*>(sR + arow * 72 + 32 + g * 8);

#pragma unroll
    for (int it = 0; it < 2; ++it) {
        int lidx = w * 1024 + it * 512 + lane * 8;
        int row = lidx >> 6;
        if (base + row < N)
            *reinterpret_cast<bf16x8*>(emb_out + (size_t)base * 64 + lidx) =
                *reinterpret_cast<const bf16x8*>(sR + row * 72 + (lidx & 63));
    }

    f32x4 z[8];
#pragma unroll
    for (int t = 0; t < 8; ++t) {
        bf16x8 b0 = *reinterpret_cast<const bf16x8*>(wfpT + (t * 16 + m16) * 64 + g * 8);
        bf16x8 b1 = *reinterpret_cast<const bf16x8*>(wfpT + (t * 16 + m16) * 64 + 32 + g * 8);
        f32x4 zz = {0.f, 0.f, 0.f, 0.f};
        zz = __builtin_amdgcn_mfma_f32_16x16x32_bf16(ra0, b0, zz, 0, 0, 0);
        zz = __builtin_amdgcn_mfma_f32_16x16x32_bf16(ra1, b1, zz, 0, 0, 0);
        float bias = bfp[t * 16 + m16];
#pragma unroll
        for (int reg = 0; reg < 4; ++reg) zz[reg] += bias;
        z[t] = zz;
    }

#pragma unroll
    for (int reg = 0; reg < 4; ++reg) {
        float mx = -1e30f;
#pragma unroll
        for (int t = 0; t < 8; ++t) mx = fmaxf(mx, z[t][reg]);
#pragma unroll
        for (int d = 1; d < 16; d <<= 1) mx = fmaxf(mx, __shfl_xor(mx, d));
        float s = 0.f;
#pragma unroll
        for (int t = 0; t < 8; ++t) {
            float p = __expf(z[t][reg] - mx);
            z[t][reg] = p;
            s += p;
        }
#pragma unroll
        for (int d = 1; d < 16; d <<= 1) s += __shfl_xor(s, d);
        int node = base + w * 16 + g * 4 + reg;
        float inv = (node < N) ? (1.f / s) : 0.f;
#pragma unroll
        for (int t = 0; t < 8; ++t) z[t][reg] *= inv;
    }
#pragma unroll
    for (int t = 0; t < 8; ++t) {
        float v = z[t][0] + z[t][1] + z[t][2] + z[t][3];
        v += __shfl_xor(v, 16);
        v += __shfl_xor(v, 32);
        if (g == 0) sFp[w][t * 16 + m16] = v;
    }
    __syncthreads();
    if (tid < 128) {
        float s = sFp[0][tid] + sFp[1][tid] + sFp[2][tid] + sFp[3][tid];
        fpart[(size_t)blockIdx.x * 128 + tid] = s;
    }
}

// stage-1 reduce: block sums RSL=32 slices (2 groups x 16, fully unrolled
// 4x4-accumulator body -> 16 independent loads in flight). Round-9 lesson:
// runtime-trip single-accumulator reduce loops serialize at HBM latency.
__global__ __launch_bounds__(256) void reduce1_kernel(const float* __restrict__ fpart,
                                                      float* __restrict__ fred, int nslice) {
    __shared__ float sAcc[128];
    int t = threadIdx.x;
    int col = t & 127, gp = t >> 7;  // 2 slice-groups
    int base = blockIdx.x * RSL + gp * (RSL / 2);
    const float* p = fpart + (size_t)base * 128 + col;
    float a0 = 0.f, a1 = 0.f, a2 = 0.f, a3 = 0.f;
    if (base + RSL / 2 <= nslice) {
#pragma unroll
        for (int k = 0; k < 4; ++k) {
            a0 += p[(k * 4 + 0) * 128];
            a1 += p[(k * 4 + 1) * 128];
            a2 += p[(k * 4 + 2) * 128];
            a3 += p[(k * 4 + 3) * 128];
        }
    } else {
        int cnt = nslice - base; if (cnt < 0) cnt = 0;
        for (int k = 0; k < cnt; ++k) a0 += p[k * 128];
    }
    float s = (a0 + a1) + (a2 + a3);
    if (gp == 1) sAcc[col] = s;
    __syncthreads();
    if (gp == 0) fred[(size_t)blockIdx.x * 128 + col] = s + sAcc[col];
}

// final: sum nred partial slices (2 groups x half, 4 accumulators) + 10-class head
__global__ __launch_bounds__(256) void final_kernel(const float* __restrict__ fred, int nred,
                                                    const float* __restrict__ Wcl,
                                                    const float* __restrict__ bcl,
                                                    float* __restrict__ out) {
    __shared__ float sAcc[128];
    __shared__ float sf[128];
    __shared__ float logits[10];
    int t = threadIdx.x;
    int col = t & 127, gp = t >> 7;
    int half = (nred + 1) >> 1;
    int b0 = gp * half;
    int b1 = b0 + half; if (b1 > nred) b1 = nred;
    float a0 = 0.f, a1 = 0.f, a2 = 0.f, a3 = 0.f;
    const float* p = fred + col;
    int b = b0;
    for (; b + 4 <= b1; b += 4) {
        a0 += p[(size_t)(b + 0) * 128];
        a1 += p[(size_t)(b + 1) * 128];
        a2 += p[(size_t)(b + 2) * 128];
        a3 += p[(size_t)(b + 3) * 128];
    }
    for (; b < b1; ++b) a0 += p[(size_t)b * 128];
    float s = (a0 + a1) + (a2 + a3);
    if (gp == 1) sAcc[col] = s;
    __syncthreads();
    if (gp == 0) sf[col] = s + sAcc[col];
    __syncthreads();
    if (t < 10) {
        float acc = bcl[t];
        for (int l = 0; l < LFP; l++) acc = fmaf(sf[l], Wcl[l * 10 + t], acc);
        logits[t] = acc;
    }
    __syncthreads();
    if (t == 0) {
        float m = -1e30f;
        for (int i = 0; i < 10; i++) m = fmaxf(m, logits[i]);
        float e[10], s2 = 0.f;
        for (int i = 0; i < 10; i++) { e[i] = __expf(logits[i] - m); s2 += e[i]; }
        for (int i = 0; i < 10; i++) out[i] = e[i] / s2;
    }
}

extern "C" void kernel_launch(void* const* d_in, const int* in_sizes, int n_in,
                              void* d_out, int out_size, void* d_ws, size_t ws_size,
                              hipStream_t stream) {
    const int* feat = (const int*)d_in[0];
    const int* esrc = (const int*)d_in[1];
    const int* edst = (const int*)d_in[2];
    const float* table = (const float*)d_in[3];
    const float* Wh = (const float*)d_in[4];
    const float* bh = (const float*)d_in[5];
    const float* Wfp = (const float*)d_in[6];
    const float* bfp = (const float*)d_in[7];
    const float* Wcl = (const float*)d_in[8];
    const float* bcl = (const float*)d_in[9];
    float* out = (float*)d_out;
    int N = in_sizes[0];
    int nE = in_sizes[1];

    int nbm = (N + BM - 1) / BM;          // mlp blocks (782)
    int nbc = (N + CB - 1) / CB;          // coarse buckets (98)
    int nbp = (nE + PCHUNK - 1) / PCHUNK; // partition blocks (196)
    int nslice = RROUNDS * nbm;           // 3128
    int nred = (nslice + RSL - 1) / RSL;  // 98

    char* ws = (char*)d_ws;
    size_t off = 0;
    auto alloc = [&](size_t bytes) { void* p = ws + off; off += (bytes + 63) & ~(size_t)63; return p; };
    unsigned short* embA = (unsigned short*)alloc((size_t)N * 64 * 2);
    unsigned short* vbuf = (unsigned short*)alloc((size_t)(N + BM) * 64 * 2);
    unsigned short* whT  = (unsigned short*)alloc(RROUNDS * 64 * 64 * 2);
    unsigned short* wfpT = (unsigned short*)alloc(RROUNDS * 128 * 64 * 2);
    float* fpart = (float*)alloc((size_t)nslice * 128 * 4);
    float* fred  = (float*)alloc((size_t)nred * 128 * 4);
    int* chist   = (int*)alloc(128 * 4);
    int* cbase   = (int*)alloc(129 * 4);
    int* ccursor = (int*)alloc(128 * 4);
    int* rp      = (int*)alloc(((size_t)N + 1) * 4);
    int* tmp     = (int*)alloc((size_t)nE * 4);
    unsigned short* csr16 = (unsigned short*)alloc((size_t)nE * 2);

    // ---- CSR build (2-level bucket sort; rebuilt every call) ----
    hipMemsetAsync(chist, 0, 128 * 4, stream);
    chist_kernel<<<nbp, 256, 0, stream>>>(edst, chist, nE, nbc);
    cscan_kernel<<<1, 128, 0, stream>>>(chist, cbase, ccursor, nbc, nE);
    partition_kernel<<<nbp, 256, 0, stream>>>(esrc, edst, ccursor, tmp, nE, nbc);
    bsort_kernel<<<nbc, 256, 0, stream>>>(cbase, tmp, csr16, rp, N, nE);

    prep_kernel<<<192, 256, 0, stream>>>(Wh, Wfp, whT, wfpT);
    init_kernel<<<(N * FDIM + 255) / 256, 256, 0, stream>>>(feat, table, embA, N);

    for (int r = 0; r < RROUNDS; ++r) {
        gather_kernel<<<(N * 64 + 255) / 256, 256, 0, stream>>>(embA, rp, csr16, vbuf, N);
        mlp_kernel<<<nbm, 256, 0, stream>>>(
            vbuf, embA, whT + (size_t)r * 4096, wfpT + (size_t)r * 8192,
            bh + (size_t)r * FDIM, bfp + (size_t)r * LFP,
            fpart + (size_t)r * nbm * 128, N);
    }

    reduce1_kernel<<<nred, 256, 0, stream>>>(fpart, fred, nslice);
    final_kernel<<<1, 256, 0, stream>>>(fred, nred, Wcl, bcl, out);
}